// Round 6
// baseline (889.062 us; speedup 1.0000x reference)
//
#include <hip/hip_runtime.h>
#include <math.h>

#define HH 2048
#define VV 128000
#define NB2 1000             // grid: all co-resident (4/CU x 256 CU = 1024 >= 1000)
#define ROWS_PER_BLOCK 128   // 1000 * 128 = 128000 = V exactly
#define TPB 256              // 4 waves

// native vector type — __builtin_nontemporal_load requires a native
// vector/scalar pointer, not HIP's float4 class type
typedef float vf4 __attribute__((ext_vector_type(4)));

__device__ __forceinline__ float wave_sum(float v) {
    #pragma unroll
    for (int off = 32; off > 0; off >>= 1) v += __shfl_down(v, off, 64);
    return v;
}

// combine two (max, sum) online-logsumexp states
__device__ __forceinline__ void lse_combine(float& m, float& s, float m2, float s2) {
    float mn = fmaxf(m, m2);
    s = s * expf(m - mn) + s2 * expf(m2 - mn);
    m = mn;
}

__device__ __forceinline__ vf4 ntload(const vf4* p) {
    return __builtin_nontemporal_load(p);
}

// Device-scope phase barrier: release own arrival, spin-acquire until all
// NB2 blocks arrived. Safe: all blocks are co-resident (see launch bounds).
__device__ __forceinline__ void phase_barrier(unsigned* cnt) {
    __syncthreads();
    if (threadIdx.x == 0) {
        __hip_atomic_fetch_add(cnt, 1u, __ATOMIC_RELEASE, __HIP_MEMORY_SCOPE_AGENT);
        while (__hip_atomic_load(cnt, __ATOMIC_ACQUIRE, __HIP_MEMORY_SCOPE_AGENT) < NB2)
            __builtin_amdgcn_s_sleep(2);
    }
    __syncthreads();
    // per-thread acquire so every thread's subsequent loads are ordered/fresh
    unsigned d = __hip_atomic_load(cnt, __ATOMIC_ACQUIRE, __HIP_MEMORY_SCOPE_AGENT);
    asm volatile("" :: "v"(d));   // keep the atomic load alive
}

// Single fused kernel (plus an 8-byte memset for the two barrier counters):
//  Phase A: LSTM cell (2-3 hidden units per block) -> h1, c1, attn_w
//  barrier
//  Phase B: 128 vocab rows per block: logits + per-block online lse partial
//  barrier
//  Phase C: every block reduces the 1000 partials (L2-resident, 8 KB),
//           then normalizes its own 128 logits in place.
__global__ __launch_bounds__(TPB, 4) void lstm_attn_fused_kernel(
    const int* __restrict__ tok, const float* __restrict__ emb,
    const float* __restrict__ W_ih, const float* __restrict__ W_hh,
    const float* __restrict__ b_ih, const float* __restrict__ b_hh,
    const float* __restrict__ h0, const float* __restrict__ c0,
    const float* __restrict__ W_out, const float* __restrict__ b_out,
    float* __restrict__ out, unsigned* __restrict__ cnt,
    float* __restrict__ part)
{
    const int b    = blockIdx.x;
    const int wave = threadIdx.x >> 6;
    const int lane = threadIdx.x & 63;

    __shared__ float h_lds[HH];
    __shared__ float g[4];
    __shared__ float red_m[4], red_s[4];
    __shared__ float lse_s;

    // ---------------- Phase A: LSTM cell ----------------
    {
        const vf4* x4 = (const vf4*)(emb + (size_t)tok[0] * HH);
        const vf4* h4 = (const vf4*)h0;

        // preload h0 (wave collectively covers all 2048 elements); skip the
        // whole W_hh stream wave-uniformly iff h0 == 0 (exact for any input)
        vf4 hreg[HH / 4 / 64];
        bool nz = false;
        #pragma unroll
        for (int it = 0; it < HH / 4 / 64; ++it) {
            hreg[it] = h4[lane + it * 64];
            nz |= (hreg[it].x != 0.f) | (hreg[it].y != 0.f) |
                  (hreg[it].z != 0.f) | (hreg[it].w != 0.f);
        }
        const bool h_nonzero = (__ballot(nz) != 0ull);

        for (int k = b; k < HH; k += NB2) {      // 2-3 hidden units per block
            const int row = wave * HH + k;       // gate row for this wave
            const vf4* wi = (const vf4*)(W_ih + (size_t)row * HH);
            float acc = 0.f;
            #pragma unroll
            for (int it = 0; it < HH / 4 / 64; ++it) {   // 8 iters
                const int i = lane + it * 64;
                vf4 a = ntload(&wi[i]), xb = x4[i];
                acc = fmaf(a.x, xb.x, fmaf(a.y, xb.y, fmaf(a.z, xb.z, fmaf(a.w, xb.w, acc))));
            }
            if (h_nonzero) {
                const vf4* wh = (const vf4*)(W_hh + (size_t)row * HH);
                #pragma unroll
                for (int it = 0; it < HH / 4 / 64; ++it) {
                    const int i = lane + it * 64;
                    vf4 c = ntload(&wh[i]), d = hreg[it];
                    acc = fmaf(c.x, d.x, fmaf(c.y, d.y, fmaf(c.z, d.z, fmaf(c.w, d.w, acc))));
                }
            }
            acc = wave_sum(acc);
            if (lane == 0) g[wave] = acc + b_ih[row] + b_hh[row];
            __syncthreads();
            if (threadIdx.x == 0) {
                float gi = 1.f / (1.f + expf(-g[0]));
                float gf = 1.f / (1.f + expf(-g[1]));
                float gg = tanhf(g[2]);
                float go = 1.f / (1.f + expf(-g[3]));
                float c1 = gf * c0[k] + gi * gg;
                float h1 = go * tanhf(c1);
                out[VV + k]      = h1;   // h_new
                out[VV + HH + k] = c1;   // c_new
            }
            __syncthreads();   // g[] reused next unit
        }
        if (b == 0 && threadIdx.x == 0)
            out[VV + 2 * HH] = 1.0f;     // softmax over length-1 axis == 1 exactly
    }

    phase_barrier(&cnt[0]);   // h1 visible to all blocks

    // ---------------- Phase B: logits + lse partial ----------------
    // feat = [h1, h1] (context == h1) so fold the two W_out halves.
    for (int i = threadIdx.x; i < HH / 4; i += TPB)
        ((vf4*)h_lds)[i] = ((const vf4*)(out + VV))[i];
    __syncthreads();

    {
        const vf4* hl = (const vf4*)h_lds;
        float m = -INFINITY, s = 0.f;      // maintained on lane 0 of each wave

        #pragma unroll 1
        for (int j = 0; j < ROWS_PER_BLOCK / 4; ++j) {   // 32 iters, 1 row/wave
            const int row = b * ROWS_PER_BLOCK + j * 4 + wave;
            const vf4* w = (const vf4*)(W_out + (size_t)row * (2 * HH));
            float acc = 0.f;
            #pragma unroll
            for (int it = 0; it < HH / 4 / 64; ++it) {   // 8 iters
                const int i = lane + it * 64;
                vf4 a  = ntload(&w[i]);
                vf4 b2 = ntload(&w[i + HH / 4]);
                vf4 hv = hl[i];
                acc = fmaf(a.x + b2.x, hv.x,
                      fmaf(a.y + b2.y, hv.y,
                      fmaf(a.z + b2.z, hv.z,
                      fmaf(a.w + b2.w, hv.w, acc))));
            }
            acc = wave_sum(acc);                          // total in lane 0
            if (lane == 0) {
                const float lg = acc + b_out[row];
                out[row] = lg;                            // raw logit
                lse_combine(m, s, lg, 1.f);
            }
        }
        if (lane == 0) { red_m[wave] = m; red_s[wave] = s; }
        __syncthreads();
        if (threadIdx.x == 0) {
            float bm = red_m[0], bs = red_s[0];
            for (int w2 = 1; w2 < 4; ++w2) lse_combine(bm, bs, red_m[w2], red_s[w2]);
            part[2 * b]     = bm;
            part[2 * b + 1] = bs;
        }
    }

    phase_barrier(&cnt[1]);   // all partials visible

    // ---------------- Phase C: lse reduce + normalize own rows ----------------
    {
        float m = -INFINITY, s = 0.f;
        for (int i = threadIdx.x; i < NB2; i += TPB)
            lse_combine(m, s, part[2 * i], part[2 * i + 1]);
        #pragma unroll
        for (int off = 32; off > 0; off >>= 1) {
            float m2 = __shfl_down(m, off, 64);
            float s2 = __shfl_down(s, off, 64);
            lse_combine(m, s, m2, s2);
        }
        if (lane == 0) { red_m[wave] = m; red_s[wave] = s; }
        __syncthreads();
        if (threadIdx.x == 0) {
            float bm = red_m[0], bs = red_s[0];
            for (int w2 = 1; w2 < 4; ++w2) lse_combine(bm, bs, red_m[w2], red_s[w2]);
            lse_s = bm + logf(bs);
        }
        __syncthreads();

        const float lse = lse_s;
        for (int t = threadIdx.x; t < ROWS_PER_BLOCK; t += TPB)
            out[b * ROWS_PER_BLOCK + t] -= lse;
    }
}

extern "C" void kernel_launch(void* const* d_in, const int* in_sizes, int n_in,
                              void* d_out, int out_size, void* d_ws, size_t ws_size,
                              hipStream_t stream) {
    const int*   tok    = (const int*)  d_in[0];
    const float* h0     = (const float*)d_in[1];
    const float* c0     = (const float*)d_in[2];
    const float* emb    = (const float*)d_in[3];
    const float* W_ih   = (const float*)d_in[4];
    const float* W_hh   = (const float*)d_in[5];
    const float* b_ih   = (const float*)d_in[6];
    const float* b_hh   = (const float*)d_in[7];
    // d_in[8..10] = W_attn, b_attn, v: unused — softmax over a length-1 axis is
    // exactly 1, so attn_w == 1.0 and context == h1 for ANY input.
    const float* W_out  = (const float*)d_in[11];
    const float* b_out  = (const float*)d_in[12];

    float*    out  = (float*)d_out;        // [0..V) logp, [V..V+H) h, [V+H..V+2H) c, [V+2H] attn_w
    unsigned* cnt  = (unsigned*)d_ws;      // 2 barrier counters
    float*    part = (float*)d_ws + 2;     // 2000 floats of lse partials

    // zero the barrier counters (graph-capturable; runs every replay)
    hipMemsetAsync(cnt, 0, 2 * sizeof(unsigned), stream);

    lstm_attn_fused_kernel<<<NB2, TPB, 0, stream>>>(
        tok, emb, W_ih, W_hh, b_ih, b_hh, h0, c0, W_out, b_out, out, cnt, part);
}

// Round 7
// 327.893 us; speedup vs baseline: 2.7114x; 2.7114x over previous
//
#include <hip/hip_runtime.h>
#include <math.h>

#define HH 2048
#define VV 128000
#define NB2 1000             // logits blocks
#define ROWS_PER_BLOCK 128   // 1000 * 128 = 128000 = V exactly
#define TPB 256              // 4 waves

// native vector type — __builtin_nontemporal_load requires a native
// vector/scalar pointer, not HIP's float4 class type
typedef float vf4 __attribute__((ext_vector_type(4)));

__device__ __forceinline__ float wave_sum(float v) {
    #pragma unroll
    for (int off = 32; off > 0; off >>= 1) v += __shfl_down(v, off, 64);
    return v;
}

// combine two (max, sum) online-logsumexp states
__device__ __forceinline__ void lse_combine(float& m, float& s, float m2, float s2) {
    float mn = fmaxf(m, m2);
    s = s * expf(m - mn) + s2 * expf(m2 - mn);
    m = mn;
}

__device__ __forceinline__ vf4 ntload(const vf4* p) {
    return __builtin_nontemporal_load(p);
}

// ---------------- Kernel A: LSTM cell ----------------
// One block per hidden unit k (2048 blocks x 256 threads).
// Wave w (0..3) computes gate row w*H + k. Thread 0 applies the cell
// nonlinearity, writes h_new/c_new (and attn_w once).
// The wave collectively reads all of h0 into registers first; if the whole
// vector is zero (ballot across the wave), the W_hh stream (67 MB) is
// skipped wave-uniformly — exact for any input, fast for h0 == 0.
__global__ __launch_bounds__(256) void lstm_cell_kernel(
    const int* __restrict__ tok, const float* __restrict__ emb,
    const float* __restrict__ W_ih, const float* __restrict__ W_hh,
    const float* __restrict__ b_ih, const float* __restrict__ b_hh,
    const float* __restrict__ h0, const float* __restrict__ c0,
    float* __restrict__ out)
{
    const int k    = blockIdx.x;
    const int wave = threadIdx.x >> 6;
    const int lane = threadIdx.x & 63;
    const int row  = wave * HH + k;

    const vf4* wi = (const vf4*)(W_ih + (size_t)row * HH);
    const vf4* wh = (const vf4*)(W_hh + (size_t)row * HH);
    const vf4* x4 = (const vf4*)(emb + (size_t)tok[0] * HH);
    const vf4* h4 = (const vf4*)h0;

    // preload h0 (wave collectively covers all 2048 elements)
    vf4 hreg[HH / 4 / 64];
    bool nz = false;
    #pragma unroll
    for (int it = 0; it < HH / 4 / 64; ++it) {
        hreg[it] = h4[lane + it * 64];
        nz |= (hreg[it].x != 0.f) | (hreg[it].y != 0.f) |
              (hreg[it].z != 0.f) | (hreg[it].w != 0.f);
    }
    const bool h_nonzero = (__ballot(nz) != 0ull);   // wave-uniform

    float acc = 0.f;
    #pragma unroll
    for (int it = 0; it < HH / 4 / 64; ++it) {   // 8 iters
        const int i = lane + it * 64;
        vf4 a = ntload(&wi[i]), b = x4[i];
        acc = fmaf(a.x, b.x, fmaf(a.y, b.y, fmaf(a.z, b.z, fmaf(a.w, b.w, acc))));
    }
    if (h_nonzero) {
        #pragma unroll
        for (int it = 0; it < HH / 4 / 64; ++it) {
            const int i = lane + it * 64;
            vf4 c = ntload(&wh[i]), d = hreg[it];
            acc = fmaf(c.x, d.x, fmaf(c.y, d.y, fmaf(c.z, d.z, fmaf(c.w, d.w, acc))));
        }
    }
    acc = wave_sum(acc);

    __shared__ float g[4];
    if (lane == 0) g[wave] = acc + b_ih[row] + b_hh[row];
    __syncthreads();

    if (threadIdx.x == 0) {
        float gi = 1.f / (1.f + expf(-g[0]));
        float gf = 1.f / (1.f + expf(-g[1]));
        float gg = tanhf(g[2]);
        float go = 1.f / (1.f + expf(-g[3]));
        float c1 = gf * c0[k] + gi * gg;
        float h1 = go * tanhf(c1);
        out[VV + k]      = h1;   // h_new
        out[VV + HH + k] = c1;   // c_new
        // softmax over a length-1 axis is exactly 1.0
        if (k == 0) out[VV + 2 * HH] = 1.0f;  // attn_w
    }
}

// ---------------- Kernel B: logits + per-block lse partial ----------------
// 1000 blocks x 256 threads; 128 contiguous rows per block (1 row per wave
// per j-iter). feat = [h1, h1] (context == h1) so fold the two W_out halves.
__global__ __launch_bounds__(TPB) void logits_lse_kernel(
    const float* __restrict__ W_out, const float* __restrict__ b_out,
    const float* __restrict__ h1g, float* __restrict__ out,
    float* __restrict__ part)
{
    const int b    = blockIdx.x;
    const int wave = threadIdx.x >> 6;
    const int lane = threadIdx.x & 63;

    __shared__ float h_lds[HH];
    __shared__ float red_m[4], red_s[4];

    for (int i = threadIdx.x; i < HH / 4; i += TPB)
        ((vf4*)h_lds)[i] = ((const vf4*)h1g)[i];
    __syncthreads();

    const vf4* hl = (const vf4*)h_lds;
    float m = -INFINITY, s = 0.f;      // maintained on lane 0 of each wave

    #pragma unroll 1
    for (int j = 0; j < ROWS_PER_BLOCK / 4; ++j) {   // 32 iters, 1 row/wave
        const int row = b * ROWS_PER_BLOCK + j * 4 + wave;
        const vf4* w = (const vf4*)(W_out + (size_t)row * (2 * HH));
        float acc = 0.f;
        #pragma unroll
        for (int it = 0; it < HH / 4 / 64; ++it) {   // 8 iters
            const int i = lane + it * 64;
            vf4 a  = ntload(&w[i]);
            vf4 b2 = ntload(&w[i + HH / 4]);
            vf4 hv = hl[i];
            acc = fmaf(a.x + b2.x, hv.x,
                  fmaf(a.y + b2.y, hv.y,
                  fmaf(a.z + b2.z, hv.z,
                  fmaf(a.w + b2.w, hv.w, acc))));
        }
        acc = wave_sum(acc);                          // total in lane 0
        if (lane == 0) {
            const float lg = acc + b_out[row];
            out[row] = lg;                            // raw logit
            lse_combine(m, s, lg, 1.f);
        }
    }
    if (lane == 0) { red_m[wave] = m; red_s[wave] = s; }
    __syncthreads();
    if (threadIdx.x == 0) {
        float bm = red_m[0], bs = red_s[0];
        for (int w2 = 1; w2 < 4; ++w2) lse_combine(bm, bs, red_m[w2], red_s[w2]);
        part[2 * b]     = bm;
        part[2 * b + 1] = bs;
    }
}

// ---------------- Kernel C: final lse reduce + normalize ----------------
// 500 blocks x 256 threads. Each block redundantly reduces the 1000
// partials (8 KB, L2-resident) then normalizes its 256 logits in place.
__global__ __launch_bounds__(TPB) void lse_norm_kernel(
    const float* __restrict__ part, float* __restrict__ out)
{
    const int wave = threadIdx.x >> 6;
    const int lane = threadIdx.x & 63;
    __shared__ float red_m[4], red_s[4];
    __shared__ float lse_s;

    float m = -INFINITY, s = 0.f;
    for (int i = threadIdx.x; i < NB2; i += TPB)
        lse_combine(m, s, part[2 * i], part[2 * i + 1]);
    #pragma unroll
    for (int off = 32; off > 0; off >>= 1) {
        float m2 = __shfl_down(m, off, 64);
        float s2 = __shfl_down(s, off, 64);
        lse_combine(m, s, m2, s2);
    }
    if (lane == 0) { red_m[wave] = m; red_s[wave] = s; }
    __syncthreads();
    if (threadIdx.x == 0) {
        float bm = red_m[0], bs = red_s[0];
        for (int w2 = 1; w2 < 4; ++w2) lse_combine(bm, bs, red_m[w2], red_s[w2]);
        lse_s = bm + logf(bs);
    }
    __syncthreads();

    const float lse = lse_s;
    const int i = blockIdx.x * TPB + threadIdx.x;
    out[i] -= lse;
}

extern "C" void kernel_launch(void* const* d_in, const int* in_sizes, int n_in,
                              void* d_out, int out_size, void* d_ws, size_t ws_size,
                              hipStream_t stream) {
    const int*   tok    = (const int*)  d_in[0];
    const float* h0     = (const float*)d_in[1];
    const float* c0     = (const float*)d_in[2];
    const float* emb    = (const float*)d_in[3];
    const float* W_ih   = (const float*)d_in[4];
    const float* W_hh   = (const float*)d_in[5];
    const float* b_ih   = (const float*)d_in[6];
    const float* b_hh   = (const float*)d_in[7];
    // d_in[8..10] = W_attn, b_attn, v: unused — softmax over a length-1 axis is
    // exactly 1, so attn_w == 1.0 and context == h1 for ANY input.
    const float* W_out  = (const float*)d_in[11];
    const float* b_out  = (const float*)d_in[12];

    float* out  = (float*)d_out;   // [0..V) logp, [V..V+H) h, [V+H..V+2H) c, [V+2H] attn_w
    float* part = (float*)d_ws;    // 2000 floats of lse partials

    // 1) LSTM cell: gates matvec + nonlinearity -> h_new, c_new, attn_w
    lstm_cell_kernel<<<HH, 256, 0, stream>>>(tok, emb, W_ih, W_hh, b_ih, b_hh, h0, c0, out);
    // 2) vocab logits (the 2.1 GB read) + per-block lse partials
    logits_lse_kernel<<<NB2, TPB, 0, stream>>>(W_out, b_out, out + VV, out, part);
    // 3) final lse reduce (redundant per block) + in-place normalize
    lse_norm_kernel<<<VV / TPB, TPB, 0, stream>>>(part, out);
}